// Round 10
// baseline (183.900 us; speedup 1.0000x reference)
//
#include <hip/hip_runtime.h>
#include <hip/hip_bf16.h>
#include <math.h>

// Problem constants
#define TSEQ 4096
#define NB 8
#define DEM 512
#define HD 64
#define WIP 136            // W chunk-image pitch (bf16): 272 B -> quad lanes 4 banks apart
#define WIMG 26624         // shorts per chunk image (53248 B = 13 * 4096, incl. tail pad)
#define QSZ ((size_t)NB * TSEQ * HD)
#define SLOTS_PER_B 144    // 8-tile segments: sum over mq of ceil((2mq+2)/8)

typedef __attribute__((ext_vector_type(8))) short short8;   // 8 bf16 MFMA frag
typedef __attribute__((ext_vector_type(4))) short short4v;  // 8B packed bf16x4
typedef __attribute__((ext_vector_type(4))) float float4v;  // 16x16 MFMA C/D frag
typedef __attribute__((ext_vector_type(16))) float f32x16;  // 32x32 MFMA C/D frag

// fp32 -> bf16 RNE (scalar)
__device__ __forceinline__ short f2bf(float f) {
    union { float f; unsigned u; } v; v.f = f;
    unsigned r = v.u + 0x7fffu + ((v.u >> 16) & 1u);
    return (short)(r >> 16);
}

// pack 8 fp32 -> short8 bf16 via v_cvt_pk
__device__ __forceinline__ short8 pack8(float4 a, float4 b) {
    union { short8 s; __hip_bfloat162 h[4]; } u;
    u.h[0] = __float22bfloat162_rn(make_float2(a.x, a.y));
    u.h[1] = __float22bfloat162_rn(make_float2(a.z, a.w));
    u.h[2] = __float22bfloat162_rn(make_float2(b.x, b.y));
    u.h[3] = __float22bfloat162_rn(make_float2(b.z, b.w));
    return u.s;
}

// pack 2 fp32 -> 1 dword of 2 bf16 (low short = first arg)
__device__ __forceinline__ int pkbf2(float x, float y) {
    union { __hip_bfloat162 h; int i; } u;
    u.h = __float22bfloat162_rn(make_float2(x, y));
    return u.i;
}

__device__ __forceinline__ short8 mk8(int a, int b, int c, int d) {
    union { short8 s; int i[4]; } u;
    u.i[0] = a; u.i[1] = b; u.i[2] = c; u.i[3] = d;
    return u.s;
}

// async global->LDS DMA, 16B per lane (dest MUST be wave-uniform base + lane*16)
__device__ __forceinline__ void gload_lds16(const void* g, void* l) {
    __builtin_amdgcn_global_load_lds(
        (const __attribute__((address_space(1))) unsigned int*)g,
        (__attribute__((address_space(3))) unsigned int*)l,
        16, 0, 0);
}

// segment bookkeeping for 8-tile segments:
//   nseg(mq) = ceil((2mq+2)/8) = (mq+4)>>2
//   slot_base(mq) = sum_{m<mq} nseg(m) = (a+1)*(2a+r), a=mq>>2, r=mq&3
__device__ __host__ __forceinline__ int slot_base(int mq) {
    int a = mq >> 2, r = mq & 3;
    return (a + 1) * (2 * a + r);
}

// ---------------------------------------------------------------------------
// W^T precompute -> 4 chunk images [192 n][136 pitch] bf16 (k-chunk c holds
// k in [128c,128c+128)), scale folded into Wq. Wq additionally folds log2(e)
// so flash uses exp2 directly. grid = (8 k-blocks, 3 matrices), 256 thr.
// ---------------------------------------------------------------------------
__global__ __launch_bounds__(256) void wtr_kernel(
    const float* __restrict__ Wq, const float* __restrict__ Wk,
    const float* __restrict__ Wv, short* __restrict__ wimg)
{
    __shared__ float t[64][65];
    const int tid = threadIdx.x;
    const int kb = blockIdx.x;           // 64-k block 0..7
    const int k0 = kb * 64;
    const int m = blockIdx.y;
    const int c = kb >> 1, half = kb & 1;
    const float* W = (m == 0) ? Wq : ((m == 1) ? Wk : Wv);
    // 512^-0.5 * log2(e): scores become log2-domain for exp2 softmax
    const float sc = (m == 0) ? (0.044194173824159216f * 1.4426950408889634f)
                              : 1.0f;

#pragma unroll
    for (int i = 0; i < 4; ++i) {
        int f = tid + 256 * i;
        int k = f >> 4, n4 = (f & 15) * 4;
        float4 wv = *(const float4*)&W[(k0 + k) * HD + n4];
        t[k][n4 + 0] = wv.x; t[k][n4 + 1] = wv.y;
        t[k][n4 + 2] = wv.z; t[k][n4 + 3] = wv.w;
    }
    __syncthreads();
#pragma unroll
    for (int i = 0; i < 4; ++i) {
        int f = tid + 256 * i;
        int n = f >> 4, k4 = (f & 15) * 4;
        short4v o;
        o[0] = f2bf(t[k4 + 0][n] * sc);
        o[1] = f2bf(t[k4 + 1][n] * sc);
        o[2] = f2bf(t[k4 + 2][n] * sc);
        o[3] = f2bf(t[k4 + 3][n] * sc);
        *(short4v*)&wimg[c * WIMG + (64 * m + n) * WIP + half * 64 + k4] = o;
    }
}

// ---------------------------------------------------------------------------
// QKV projection: W^T chunk staged in LDS via global_load_lds(16B), shared by
// all 4 waves; x rows for chunk c+1 register-prefetched right after the stage
// barrier (T14). Block: 256 thr = 64 rows; grid 512. (256,3): 3 blocks/CU.
// ---------------------------------------------------------------------------
__global__ __launch_bounds__(256, 3) void qkv_mfma(
    const float* __restrict__ x, const short* __restrict__ wimg,
    short* __restrict__ q, short* __restrict__ k, short* __restrict__ vt)
{
    __shared__ alignas(16) short wlds[WIMG];   // 53.2 KB, one chunk image

    const int tid = threadIdx.x;
    const int w = tid >> 6;
    const int l15 = tid & 15;
    const int quad = (tid >> 4) & 3;
    const int rbase = blockIdx.x * 64 + w * 16 + l15;   // global row (b*T + t)

    const float* xr = x + (size_t)rbase * DEM;
    float4v acc[12] = {};

    float4 xa[4], xb[4];                 // x prefetch regs (32 VGPR)
#pragma unroll
    for (int ks = 0; ks < 4; ++ks) {
        xa[ks] = *(const float4*)&xr[ks * 32 + quad * 8];
        xb[ks] = *(const float4*)&xr[ks * 32 + quad * 8 + 4];
    }

    for (int c = 0; c < 4; ++c) {
        __syncthreads();                 // previous chunk's reads complete
        {
            const char* gsrc = (const char*)(wimg + c * WIMG) + tid * 16;
            char* ldst = (char*)wlds + tid * 16;
#pragma unroll
            for (int i = 0; i < 13; ++i)
                gload_lds16(gsrc + i * 4096, ldst + i * 4096);
        }
        short8 xv[4];                    // convert this chunk's x while DMA flies
#pragma unroll
        for (int ks = 0; ks < 4; ++ks) xv[ks] = pack8(xa[ks], xb[ks]);
        __syncthreads();                 // vmcnt(0)+barrier: DMA landed

        if (c + 1 < 4) {                 // prefetch next chunk's x (issue-early)
#pragma unroll
            for (int ks = 0; ks < 4; ++ks) {
                xa[ks] = *(const float4*)&xr[(c + 1) * 128 + ks * 32 + quad * 8];
                xb[ks] = *(const float4*)&xr[(c + 1) * 128 + ks * 32 + quad * 8 + 4];
            }
        }

#pragma unroll
        for (int ks = 0; ks < 4; ++ks) {
            const int lk = ks * 32 + quad * 8;
#pragma unroll
            for (int mt = 0; mt < 12; ++mt) {
                short8 wf = *(const short8*)&wlds[(mt * 16 + l15) * WIP + lk];
                acc[mt] = __builtin_amdgcn_mfma_f32_16x16x32_bf16(wf, xv[ks], acc[mt], 0, 0, 0);
            }
        }
    }

    // Epilogue. C^T frag: row = n_out = mt*16+quad*4+reg, col = t = rbase.
#pragma unroll
    for (int mt = 0; mt < 8; ++mt) {     // q (mt<4), k (mt 4..7): packed 8B
        short* dst = (mt < 4) ? q : k;
        short4v o;
        o[0] = f2bf(acc[mt][0]); o[1] = f2bf(acc[mt][1]);
        o[2] = f2bf(acc[mt][2]); o[3] = f2bf(acc[mt][3]);
        *(short4v*)&dst[(size_t)rbase * HD + (mt & 3) * 16 + quad * 4] = o;
    }
    const int b = rbase >> 12, t = rbase & (TSEQ - 1);
#pragma unroll
    for (int mt = 8; mt < 12; ++mt) {    // v transposed: scalar bf16 stores
#pragma unroll
        for (int reg = 0; reg < 4; ++reg) {
            int d = (mt - 8) * 16 + quad * 4 + reg;
            vt[((size_t)(b * HD + d)) * TSEQ + t] = f2bf(acc[mt][reg]);
        }
    }
}

// ---------------------------------------------------------------------------
// Flash attention phase A — round-8 skeleton with the LDS staging DELETED.
// Insight: in the 1-wave design both MFMA operand fragments are EXACT
// contiguous 16B global slices:
//   K A-frag  = K[ss*32+q5][ks*16+hi*8 ..+8]          (contiguous in kw)
//   V B-frag  = V^T[dh*32+q5][ss*32+kr*16+hi*8 ..+8]  (contiguous in vt)
// so the global->reg->ds_write->barrier->drain->ds_read chain (16 LDS ops,
// 2 barriers, 2.1M bank-conflict cycles/dispatch) is pure overhead. Replace
// with direct global->VGPR fragment loads, ping-pong double-buffered one
// step ahead (explicit A/B unroll-by-2: static register indexing, pipeline
// encoded in dataflow -> nothing for the scheduler to sink, no fences
// needed). Same bytes/step from L2 (8KB, each byte once). LDS = 0.
// Grid = 8 batches x 144 segments x 4 row-quarters = 4608 x 64 thr.
// NO launch_bounds min-waves arg (the R5/R6 64-VGPR squeeze lesson).
// ---------------------------------------------------------------------------
__global__ __launch_bounds__(64) void flash_mfma(
    const short* __restrict__ qw, const short* __restrict__ kw,
    const short* __restrict__ vtw, float* __restrict__ out,
    float* __restrict__ pO, float* __restrict__ stS)
{
    const int lane = threadIdx.x;        // 0..63
    const int q5 = lane & 31;            // q column (and key row for A-frags)
    const int hi = lane >> 5;
    const int bx = blockIdx.x;
    const int b = bx & 7;                // XCD<->batch affinity
    const int r = bx >> 3;
    const int w = r & 3;                 // 32-row quarter within 128-row group
    const int idx = r >> 2;              // 0..143, descending cost

    int mq, j;
    if (idx < 120) {                     // full 8-tile (16-step) segments
        int t = idx;
        mq = 31; j = 0;
#pragma unroll 1
        for (int mm = 31; mm >= 3; --mm) {
            int f = (mm + 1) >> 2;       // # full segments for mm
            if (t < f) { mq = mm; j = t; break; }
            t -= f;
        }
    } else {                             // tail segments: sizes 6,4,2 tiles
        int t = idx - 120;               // 0..23
        int kc = t >> 3, p = t & 7;
        mq = (30 - kc) - 4 * p;
        j = (mq + 1) >> 2;               // last (partial) segment index
    }
    const int r0 = mq * 128;
    const int ss0 = 16 * j;              // 32-key steps
    // last step this wave needs: keys <= r0+32w+31  ->  step 4mq+w
    const int ssend = min(16 * (j + 1), 4 * mq + w + 1);
    const int slot = b * SLOTS_PER_B + slot_base(mq) + j;
    const int qrow = r0 + w * 32 + q5;

    // Q B-frags (pre-scaled by 512^-0.5*log2e via Wq)
    short8 qf[4];
    {
        const short* qp = qw + ((size_t)(b * TSEQ + qrow)) * HD + hi * 8;
#pragma unroll
        for (int ks = 0; ks < 4; ++ks) qf[ks] = *(const short8*)(qp + ks * 16);
    }

    f32x16 O0 = {}, O1 = {};             // O[d 0..31], O[d 32..63]
    float l_lane = 0.f;                  // half-denominator for q=q5

    // per-lane fragment base pointers (constant across steps)
    const short* kfb  = kw  + ((size_t)(b * TSEQ) + q5) * HD + hi * 8;        // + ss*32*HD + ks*16
    const short* vfb0 = vtw + ((size_t)(b * HD + q5)) * TSEQ + hi * 8;        // + ss*32 + kr*16
    const short* vfb1 = vtw + ((size_t)(b * HD + 32 + q5)) * TSEQ + hi * 8;

    short8 ka[4], va[4], kb_[4], vb_[4]; // ping-pong fragment buffers

    // fragment loader: k[ks] = K[ss*32+q5][ks*16+hi*8..], v[0..1]=d-half0 kr0/1,
    // v[2..3]=d-half1 kr0/1
    auto LOADF = [&](short8* kf, short8* vf, int ss) {
        const short* kp  = kfb  + (size_t)ss * 32 * HD;
        const short* vp0 = vfb0 + ss * 32;
        const short* vp1 = vfb1 + ss * 32;
        kf[0] = *(const short8*)(kp);
        kf[1] = *(const short8*)(kp + 16);
        kf[2] = *(const short8*)(kp + 32);
        kf[3] = *(const short8*)(kp + 48);
        vf[0] = *(const short8*)(vp0);
        vf[1] = *(const short8*)(vp0 + 16);
        vf[2] = *(const short8*)(vp1);
        vf[3] = *(const short8*)(vp1 + 16);
    };

    // one K/V step: S^T = K@Q^T, mask, exp2 softmax, pack/shfl, O += P@V
    auto STEP = [&](const short8* kf, const short8* vf, int ss) {
        f32x16 S = {};
#pragma unroll
        for (int ks = 0; ks < 4; ++ks)
            S = __builtin_amdgcn_mfma_f32_32x32x16_bf16(kf[ks], qf[ks], S, 0, 0, 0);

        if (ss * 32 + 31 > r0 + w * 32) {        // causal mask, diagonal steps
#pragma unroll
            for (int reg = 0; reg < 16; ++reg) {
                int key = ss * 32 + (reg & 3) + 8 * (reg >> 2) + 4 * hi;
                if (key > qrow) S[reg] = -INFINITY;
            }
        }

        float p[16];
#pragma unroll
        for (int reg = 0; reg < 16; ++reg) {
            p[reg] = __builtin_amdgcn_exp2f(S[reg]);
            l_lane += p[reg];
        }
        int dd[4][2];
#pragma unroll
        for (int a = 0; a < 4; ++a) {
            dd[a][0] = pkbf2(p[4 * a + 0], p[4 * a + 1]);
            dd[a][1] = pkbf2(p[4 * a + 2], p[4 * a + 3]);
        }
        int ra0 = __shfl_xor(hi ? dd[0][0] : dd[1][0], 32, 64);
        int ra1 = __shfl_xor(hi ? dd[0][1] : dd[1][1], 32, 64);
        int rb0 = __shfl_xor(hi ? dd[2][0] : dd[3][0], 32, 64);
        int rb1 = __shfl_xor(hi ? dd[2][1] : dd[3][1], 32, 64);
        short8 PA0 = hi ? mk8(ra0, ra1, dd[1][0], dd[1][1])
                        : mk8(dd[0][0], dd[0][1], ra0, ra1);
        short8 PA1 = hi ? mk8(rb0, rb1, dd[3][0], dd[3][1])
                        : mk8(dd[2][0], dd[2][1], rb0, rb1);

        O0 = __builtin_amdgcn_mfma_f32_32x32x16_bf16(PA0, vf[0], O0, 0, 0, 0);
        O0 = __builtin_amdgcn_mfma_f32_32x32x16_bf16(PA1, vf[1], O0, 0, 0, 0);
        O1 = __builtin_amdgcn_mfma_f32_32x32x16_bf16(PA0, vf[2], O1, 0, 0, 0);
        O1 = __builtin_amdgcn_mfma_f32_32x32x16_bf16(PA1, vf[3], O1, 0, 0, 0);
    };

    // software pipeline: buffer A holds step ss, B holds ss+1; loads for
    // ss+2 are issued between STEP(ss) and STEP(ss+1) -> one full step of
    // latency cover, zero register moves, all indices compile-time.
    LOADF(ka, va, ss0);
    int ss = ss0;
#pragma unroll 1
    for (; ss + 1 < ssend; ss += 2) {
        LOADF(kb_, vb_, ss + 1);
        STEP(ka, va, ss);
        if (ss + 2 < ssend) LOADF(ka, va, ss + 2);
        STEP(kb_, vb_, ss + 1);
    }
    if (ss < ssend) STEP(ka, va, ss);    // odd-count tail

    const float ltot = l_lane + __shfl_xor(l_lane, 32, 64);  // full denom, q=q5

    if (mq <= 3) {
        // single segment: normalize and write final output directly
        float inv = 1.0f / ltot;
#pragma unroll
        for (int reg = 0; reg < 16; ++reg) {
            int qloc = (reg & 3) + 8 * (reg >> 2) + 4 * hi;
            float ir = __shfl(inv, qloc, 64);
            size_t rowb = (size_t)(b * TSEQ + r0 + w * 32 + qloc) * HD + q5;
            out[rowb]      = O0[reg] * ir;
            out[rowb + 32] = O1[reg] * ir;
        }
    } else {
        float* dest = pO + ((size_t)slot * 128 + w * 32) * HD + q5;
#pragma unroll
        for (int reg = 0; reg < 16; ++reg) {
            int qloc = (reg & 3) + 8 * (reg >> 2) + 4 * hi;
            dest[(size_t)qloc * HD]      = O0[reg];
            dest[(size_t)qloc * HD + 32] = O1[reg];
        }
        if (hi == 0) stS[slot * 128 + w * 32 + q5] = ltot;
    }
}

// ---------------------------------------------------------------------------
// Merge: rows with mq>=4 only (2..8 segments). 64 rows/block, 4 threads/row.
// grid = 8 batches x 56 blocks = 448.
// ---------------------------------------------------------------------------
__global__ __launch_bounds__(256) void merge_kernel(
    float* __restrict__ out, const float* __restrict__ pO,
    const float* __restrict__ stS)
{
    const int tid = threadIdx.x;
    const int bx = blockIdx.x;
    const int b = bx / 56, loc = bx - b * 56;
    const int t = 512 + loc * 64 + (tid >> 2);       // row within batch
    const int dq = (tid & 3) * 16;
    const int mq = t >> 7, rr = t & 127;
    const int nseg = (mq + 4) >> 2;                  // ceil((2mq+2)/8)
    const int sb = b * SLOTS_PER_B + slot_base(mq);

    float denom = 0.f;
    for (int s = 0; s < nseg; ++s) denom += stS[(sb + s) * 128 + rr];
    float inv = 1.0f / denom;

    float4 o[4] = {};
    for (int s = 0; s < nseg; ++s) {
        const float4* pp = (const float4*)
            &pO[((size_t)(sb + s) * 128 + rr) * HD + dq];
#pragma unroll
        for (int i = 0; i < 4; ++i) {
            float4 p = pp[i];
            o[i].x += p.x; o[i].y += p.y;
            o[i].z += p.z; o[i].w += p.w;
        }
    }
    float4* op = (float4*)&out[((size_t)b * TSEQ + t) * HD + dq];
#pragma unroll
    for (int i = 0; i < 4; ++i) {
        o[i].x *= inv; o[i].y *= inv; o[i].z *= inv; o[i].w *= inv;
        op[i] = o[i];
    }
}

extern "C" void kernel_launch(void* const* d_in, const int* in_sizes, int n_in,
                              void* d_out, int out_size, void* d_ws, size_t ws_size,
                              hipStream_t stream) {
    const float* x  = (const float*)d_in[0];   // [8, 4096, 512]
    const float* Wq = (const float*)d_in[1];   // [512, 64]
    const float* Wk = (const float*)d_in[2];
    const float* Wv = (const float*)d_in[3];
    float* out = (float*)d_out;                // [8, 4096, 64] fp32

    short* q  = (short*)d_ws;                  // bf16 [8*4096][64], pre-scaled (incl log2e)
    short* k  = q + QSZ;                       // bf16 [8*4096][64]
    short* vt = k + QSZ;                       // bf16 [8][64][4096] (transposed)
    short* wimg = vt + QSZ;                    // 4 x chunk image [192][136] bf16
    float* pO = (float*)(wimg + 4 * WIMG);     // 1152 slots x [128][64] fp32 = 37.7 MB
    float* stS = pO + (size_t)NB * SLOTS_PER_B * 128 * HD;  // 1152 x 128 denominators

    wtr_kernel<<<dim3(8, 3), 256, 0, stream>>>(Wq, Wk, Wv, wimg);
    qkv_mfma<<<dim3(NB * TSEQ / 64), 256, 0, stream>>>(x, wimg, q, k, vt);
    flash_mfma<<<dim3(NB * SLOTS_PER_B * 4), 64, 0, stream>>>(q, k, vt, out, pO, stS);
    merge_kernel<<<dim3(448), 256, 0, stream>>>(out, pO, stS);
}

// Round 11
// 153.967 us; speedup vs baseline: 1.1944x; 1.1944x over previous
//
#include <hip/hip_runtime.h>
#include <hip/hip_bf16.h>
#include <math.h>

// Problem constants
#define TSEQ 4096
#define NB 8
#define DEM 512
#define HD 64
#define KP 66              // flash K-tile LDS pitch (shorts): 33 dwords (odd) -> <=2-way banks
#define VP 34              // flash V^T-tile LDS pitch (shorts): 17 dwords (odd) -> <=2-way banks
#define WIP 136            // W chunk-image pitch (bf16): 272 B -> quad lanes 4 banks apart
#define WIMG 26624         // shorts per chunk image (53248 B = 13 * 4096, incl. tail pad)
#define QSZ ((size_t)NB * TSEQ * HD)
#define SLOTS_PER_B 144    // 8-tile segments: sum over mq of ceil((2mq+2)/8)

typedef __attribute__((ext_vector_type(8))) short short8;   // 8 bf16 MFMA frag
typedef __attribute__((ext_vector_type(4))) short short4v;  // 8B packed bf16x4
typedef __attribute__((ext_vector_type(4))) float float4v;  // 16x16 MFMA C/D frag
typedef __attribute__((ext_vector_type(16))) float f32x16;  // 32x32 MFMA C/D frag

// fp32 -> bf16 RNE (scalar)
__device__ __forceinline__ short f2bf(float f) {
    union { float f; unsigned u; } v; v.f = f;
    unsigned r = v.u + 0x7fffu + ((v.u >> 16) & 1u);
    return (short)(r >> 16);
}

// pack 8 fp32 -> short8 bf16 via v_cvt_pk
__device__ __forceinline__ short8 pack8(float4 a, float4 b) {
    union { short8 s; __hip_bfloat162 h[4]; } u;
    u.h[0] = __float22bfloat162_rn(make_float2(a.x, a.y));
    u.h[1] = __float22bfloat162_rn(make_float2(a.z, a.w));
    u.h[2] = __float22bfloat162_rn(make_float2(b.x, b.y));
    u.h[3] = __float22bfloat162_rn(make_float2(b.z, b.w));
    return u.s;
}

// pack 2 fp32 -> 1 dword of 2 bf16 (low short = first arg)
__device__ __forceinline__ int pkbf2(float x, float y) {
    union { __hip_bfloat162 h; int i; } u;
    u.h = __float22bfloat162_rn(make_float2(x, y));
    return u.i;
}

__device__ __forceinline__ short8 mk8(int a, int b, int c, int d) {
    union { short8 s; int i[4]; } u;
    u.i[0] = a; u.i[1] = b; u.i[2] = c; u.i[3] = d;
    return u.s;
}

// async global->LDS DMA, 16B per lane (dest MUST be wave-uniform base + lane*16)
__device__ __forceinline__ void gload_lds16(const void* g, void* l) {
    __builtin_amdgcn_global_load_lds(
        (const __attribute__((address_space(1))) unsigned int*)g,
        (__attribute__((address_space(3))) unsigned int*)l,
        16, 0, 0);
}

// segment bookkeeping for 8-tile segments:
//   nseg(mq) = ceil((2mq+2)/8) = (mq+4)>>2
//   slot_base(mq) = sum_{m<mq} nseg(m) = (a+1)*(2a+r), a=mq>>2, r=mq&3
__device__ __host__ __forceinline__ int slot_base(int mq) {
    int a = mq >> 2, r = mq & 3;
    return (a + 1) * (2 * a + r);
}

// ---------------------------------------------------------------------------
// W^T precompute -> 4 chunk images [192 n][136 pitch] bf16 (k-chunk c holds
// k in [128c,128c+128)), scale folded into Wq. Wq additionally folds log2(e)
// so flash uses exp2 directly. grid = (8 k-blocks, 3 matrices), 256 thr.
// ---------------------------------------------------------------------------
__global__ __launch_bounds__(256) void wtr_kernel(
    const float* __restrict__ Wq, const float* __restrict__ Wk,
    const float* __restrict__ Wv, short* __restrict__ wimg)
{
    __shared__ float t[64][65];
    const int tid = threadIdx.x;
    const int kb = blockIdx.x;           // 64-k block 0..7
    const int k0 = kb * 64;
    const int m = blockIdx.y;
    const int c = kb >> 1, half = kb & 1;
    const float* W = (m == 0) ? Wq : ((m == 1) ? Wk : Wv);
    // 512^-0.5 * log2(e): scores become log2-domain for exp2 softmax
    const float sc = (m == 0) ? (0.044194173824159216f * 1.4426950408889634f)
                              : 1.0f;

#pragma unroll
    for (int i = 0; i < 4; ++i) {
        int f = tid + 256 * i;
        int k = f >> 4, n4 = (f & 15) * 4;
        float4 wv = *(const float4*)&W[(k0 + k) * HD + n4];
        t[k][n4 + 0] = wv.x; t[k][n4 + 1] = wv.y;
        t[k][n4 + 2] = wv.z; t[k][n4 + 3] = wv.w;
    }
    __syncthreads();
#pragma unroll
    for (int i = 0; i < 4; ++i) {
        int f = tid + 256 * i;
        int n = f >> 4, k4 = (f & 15) * 4;
        short4v o;
        o[0] = f2bf(t[k4 + 0][n] * sc);
        o[1] = f2bf(t[k4 + 1][n] * sc);
        o[2] = f2bf(t[k4 + 2][n] * sc);
        o[3] = f2bf(t[k4 + 3][n] * sc);
        *(short4v*)&wimg[c * WIMG + (64 * m + n) * WIP + half * 64 + k4] = o;
    }
}

// ---------------------------------------------------------------------------
// QKV projection: W^T chunk staged in LDS via global_load_lds(16B), shared by
// all 4 waves; x rows for chunk c+1 register-prefetched right after the stage
// barrier (T14). Block: 256 thr = 64 rows; grid 512. (256,3): 3 blocks/CU.
// ---------------------------------------------------------------------------
__global__ __launch_bounds__(256, 3) void qkv_mfma(
    const float* __restrict__ x, const short* __restrict__ wimg,
    short* __restrict__ q, short* __restrict__ k, short* __restrict__ vt)
{
    __shared__ alignas(16) short wlds[WIMG];   // 53.2 KB, one chunk image

    const int tid = threadIdx.x;
    const int w = tid >> 6;
    const int l15 = tid & 15;
    const int quad = (tid >> 4) & 3;
    const int rbase = blockIdx.x * 64 + w * 16 + l15;   // global row (b*T + t)

    const float* xr = x + (size_t)rbase * DEM;
    float4v acc[12] = {};

    float4 xa[4], xb[4];                 // x prefetch regs (32 VGPR)
#pragma unroll
    for (int ks = 0; ks < 4; ++ks) {
        xa[ks] = *(const float4*)&xr[ks * 32 + quad * 8];
        xb[ks] = *(const float4*)&xr[ks * 32 + quad * 8 + 4];
    }

    for (int c = 0; c < 4; ++c) {
        __syncthreads();                 // previous chunk's reads complete
        {
            const char* gsrc = (const char*)(wimg + c * WIMG) + tid * 16;
            char* ldst = (char*)wlds + tid * 16;
#pragma unroll
            for (int i = 0; i < 13; ++i)
                gload_lds16(gsrc + i * 4096, ldst + i * 4096);
        }
        short8 xv[4];                    // convert this chunk's x while DMA flies
#pragma unroll
        for (int ks = 0; ks < 4; ++ks) xv[ks] = pack8(xa[ks], xb[ks]);
        __syncthreads();                 // vmcnt(0)+barrier: DMA landed

        if (c + 1 < 4) {                 // prefetch next chunk's x (issue-early)
#pragma unroll
            for (int ks = 0; ks < 4; ++ks) {
                xa[ks] = *(const float4*)&xr[(c + 1) * 128 + ks * 32 + quad * 8];
                xb[ks] = *(const float4*)&xr[(c + 1) * 128 + ks * 32 + quad * 8 + 4];
            }
        }

#pragma unroll
        for (int ks = 0; ks < 4; ++ks) {
            const int lk = ks * 32 + quad * 8;
#pragma unroll
            for (int mt = 0; mt < 12; ++mt) {
                short8 wf = *(const short8*)&wlds[(mt * 16 + l15) * WIP + lk];
                acc[mt] = __builtin_amdgcn_mfma_f32_16x16x32_bf16(wf, xv[ks], acc[mt], 0, 0, 0);
            }
        }
    }

    // Epilogue. C^T frag: row = n_out = mt*16+quad*4+reg, col = t = rbase.
#pragma unroll
    for (int mt = 0; mt < 8; ++mt) {     // q (mt<4), k (mt 4..7): packed 8B
        short* dst = (mt < 4) ? q : k;
        short4v o;
        o[0] = f2bf(acc[mt][0]); o[1] = f2bf(acc[mt][1]);
        o[2] = f2bf(acc[mt][2]); o[3] = f2bf(acc[mt][3]);
        *(short4v*)&dst[(size_t)rbase * HD + (mt & 3) * 16 + quad * 4] = o;
    }
    const int b = rbase >> 12, t = rbase & (TSEQ - 1);
#pragma unroll
    for (int mt = 8; mt < 12; ++mt) {    // v transposed: scalar bf16 stores
#pragma unroll
        for (int reg = 0; reg < 4; ++reg) {
            int d = (mt - 8) * 16 + quad * 4 + reg;
            vt[((size_t)(b * HD + d)) * TSEQ + t] = f2bf(acc[mt][reg]);
        }
    }
}

// ---------------------------------------------------------------------------
// Flash attention phase A — the measured champion (round 8: flash 43.3 us,
// total 154.4 us). One wave per 64-thread block; per-wave private LDS tiles;
// TWO __syncthreads per step. In a 1-wave WG the s_barrier is elided but the
// intrinsic remains a compiler scheduling fence + waitcnt point: it pins the
// register K/V prefetch exactly one step ahead of use. Six structural
// neighbors (multi-wave packing x3, 64-key steps, 2x rows, direct-global
// frags) all measured 47-140 us — this schedule is a sharp local optimum:
// barrier-fenced LDS staging converts operand reads to ds_read latency
// class while the global fill flies one full step in the background.
// exp2 softmax (log2e folded into Wq). Grid = 8 x 144 x 4 = 4608 x 64 thr.
// ---------------------------------------------------------------------------
__global__ __launch_bounds__(64, 3) void flash_mfma(
    const short* __restrict__ qw, const short* __restrict__ kw,
    const short* __restrict__ vtw, float* __restrict__ out,
    float* __restrict__ pO, float* __restrict__ stS)
{
    __shared__ short kt[32 * KP];        // K step tile [32 key][64 d]
    __shared__ short vl[64 * VP];        // V^T step tile [64 d][32 key]

    const int lane = threadIdx.x;        // 0..63
    const int q5 = lane & 31;            // q column (and key row for A-frags)
    const int hi = lane >> 5;
    const int bx = blockIdx.x;
    const int b = bx & 7;                // XCD<->batch affinity
    const int r = bx >> 3;
    const int w = r & 3;                 // 32-row quarter within 128-row group
    const int idx = r >> 2;              // 0..143, descending cost

    int mq, j;
    if (idx < 120) {                     // full 8-tile (16-step) segments
        int t = idx;
        mq = 31; j = 0;
#pragma unroll 1
        for (int mm = 31; mm >= 3; --mm) {
            int f = (mm + 1) >> 2;       // # full segments for mm
            if (t < f) { mq = mm; j = t; break; }
            t -= f;
        }
    } else {                             // tail segments: sizes 6,4,2 tiles
        int t = idx - 120;               // 0..23
        int kc = t >> 3, p = t & 7;
        mq = (30 - kc) - 4 * p;
        j = (mq + 1) >> 2;               // last (partial) segment index
    }
    const int r0 = mq * 128;
    const int ss0 = 16 * j;              // 32-key steps
    // last step this wave needs: keys <= r0+32w+31  ->  step 4mq+w
    const int ssend = min(16 * (j + 1), 4 * mq + w + 1);
    const int slot = b * SLOTS_PER_B + slot_base(mq) + j;
    const int qrow = r0 + w * 32 + q5;

    // Q B-frags (pre-scaled by 512^-0.5*log2e via Wq)
    short8 qf[4];
    {
        const short* qp = qw + ((size_t)(b * TSEQ + qrow)) * HD + hi * 8;
#pragma unroll
        for (int ks = 0; ks < 4; ++ks) qf[ks] = *(const short8*)(qp + ks * 16);
    }

    f32x16 O0 = {}, O1 = {};             // O[d 0..31], O[d 32..63]
    float l_lane = 0.f;                  // half-denominator for q=q5

    const short* kbase = kw + (size_t)b * TSEQ * HD;
    const short* vbase = vtw + (size_t)b * HD * TSEQ;
    const int krow = lane >> 3, kc8 = (lane & 7) * 8;   // K stage coords
    const int vrow = lane >> 2, vc8 = (lane & 3) * 8;   // V stage coords

    short8 pk0, pk1, pk2, pk3, pv0, pv1, pv2, pv3;      // stage prefetch regs
    {
        const short* kg = kbase + (size_t)(ss0 * 32) * HD;
        const short* vg = vbase + ss0 * 32;
        pk0 = *(const short8*)(kg + (krow +  0) * HD + kc8);
        pk1 = *(const short8*)(kg + (krow +  8) * HD + kc8);
        pk2 = *(const short8*)(kg + (krow + 16) * HD + kc8);
        pk3 = *(const short8*)(kg + (krow + 24) * HD + kc8);
        pv0 = *(const short8*)(vg + (size_t)(vrow +  0) * TSEQ + vc8);
        pv1 = *(const short8*)(vg + (size_t)(vrow + 16) * TSEQ + vc8);
        pv2 = *(const short8*)(vg + (size_t)(vrow + 32) * TSEQ + vc8);
        pv3 = *(const short8*)(vg + (size_t)(vrow + 48) * TSEQ + vc8);
    }

    for (int ss = ss0; ss < ssend; ++ss) {
        __syncthreads();                 // 1-wave WG: sched fence, pins pipeline
        *(short8*)&kt[(krow +  0) * KP + kc8] = pk0;
        *(short8*)&kt[(krow +  8) * KP + kc8] = pk1;
        *(short8*)&kt[(krow + 16) * KP + kc8] = pk2;
        *(short8*)&kt[(krow + 24) * KP + kc8] = pk3;
        *(short8*)&vl[(vrow +  0) * VP + vc8] = pv0;
        *(short8*)&vl[(vrow + 16) * VP + vc8] = pv1;
        *(short8*)&vl[(vrow + 32) * VP + vc8] = pv2;
        *(short8*)&vl[(vrow + 48) * VP + vc8] = pv3;
        __syncthreads();                 // writes visible (lgkmcnt drain)

        if (ss + 1 < ssend) {            // prefetch next step (pinned here)
            const short* kg = kbase + (size_t)((ss + 1) * 32) * HD;
            const short* vg = vbase + (ss + 1) * 32;
            pk0 = *(const short8*)(kg + (krow +  0) * HD + kc8);
            pk1 = *(const short8*)(kg + (krow +  8) * HD + kc8);
            pk2 = *(const short8*)(kg + (krow + 16) * HD + kc8);
            pk3 = *(const short8*)(kg + (krow + 24) * HD + kc8);
            pv0 = *(const short8*)(vg + (size_t)(vrow +  0) * TSEQ + vc8);
            pv1 = *(const short8*)(vg + (size_t)(vrow + 16) * TSEQ + vc8);
            pv2 = *(const short8*)(vg + (size_t)(vrow + 32) * TSEQ + vc8);
            pv3 = *(const short8*)(vg + (size_t)(vrow + 48) * TSEQ + vc8);
        }

        // S^T = K @ Q^T over 4 d-slices; D[col=q5][row=key (reg&3)+8(reg>>2)+4hi]
        f32x16 S = {};
#pragma unroll
        for (int ks = 0; ks < 4; ++ks) {
            short8 a = *(const short8*)&kt[q5 * KP + ks * 16 + hi * 8];
            S = __builtin_amdgcn_mfma_f32_32x32x16_bf16(a, qf[ks], S, 0, 0, 0);
        }

        // causal mask (wave-uniform branch; only diagonal-band steps)
        if (ss * 32 + 31 > r0 + w * 32) {
#pragma unroll
            for (int reg = 0; reg < 16; ++reg) {
                int key = ss * 32 + (reg & 3) + 8 * (reg >> 2) + 4 * hi;
                if (key > qrow) S[reg] = -INFINITY;
            }
        }

        // fixed-max softmax in log2 domain: p = exp2(S); exp2(-inf)=0
        float p[16];
#pragma unroll
        for (int reg = 0; reg < 16; ++reg) {
            p[reg] = __builtin_amdgcn_exp2f(S[reg]);
            l_lane += p[reg];
        }
        // pack to bf16: dd[a][e] = keys (8a+4hi+2e, +1) of row q5
        int dd[4][2];
#pragma unroll
        for (int a = 0; a < 4; ++a) {
            dd[a][0] = pkbf2(p[4 * a + 0], p[4 * a + 1]);
            dd[a][1] = pkbf2(p[4 * a + 2], p[4 * a + 3]);
        }
        // exchange halves: lane(hi) needs partner's m in {hi, 2+hi}
        int ra0 = __shfl_xor(hi ? dd[0][0] : dd[1][0], 32, 64);
        int ra1 = __shfl_xor(hi ? dd[0][1] : dd[1][1], 32, 64);
        int rb0 = __shfl_xor(hi ? dd[2][0] : dd[3][0], 32, 64);
        int rb1 = __shfl_xor(hi ? dd[2][1] : dd[3][1], 32, 64);
        // PA[kr]: A[row=q5][k = kr*16 + hi*8 + 0..7]  (m = 2kr + hi)
        short8 PA0 = hi ? mk8(ra0, ra1, dd[1][0], dd[1][1])
                        : mk8(dd[0][0], dd[0][1], ra0, ra1);
        short8 PA1 = hi ? mk8(rb0, rb1, dd[3][0], dd[3][1])
                        : mk8(dd[2][0], dd[2][1], rb0, rb1);

        // O += P @ V : B[k=key][col=d] from vl
#pragma unroll
        for (int kr = 0; kr < 2; ++kr) {
            short8 pa = kr ? PA1 : PA0;
            short8 v0 = *(const short8*)&vl[(q5)      * VP + kr * 16 + hi * 8];
            short8 v1 = *(const short8*)&vl[(32 + q5) * VP + kr * 16 + hi * 8];
            O0 = __builtin_amdgcn_mfma_f32_32x32x16_bf16(pa, v0, O0, 0, 0, 0);
            O1 = __builtin_amdgcn_mfma_f32_32x32x16_bf16(pa, v1, O1, 0, 0, 0);
        }
    }

    const float ltot = l_lane + __shfl_xor(l_lane, 32, 64);  // full denom, q=q5

    if (mq <= 3) {
        // single segment: normalize and write final output directly
        float inv = 1.0f / ltot;
#pragma unroll
        for (int reg = 0; reg < 16; ++reg) {
            int qloc = (reg & 3) + 8 * (reg >> 2) + 4 * hi;
            float ir = __shfl(inv, qloc, 64);
            size_t rowb = (size_t)(b * TSEQ + r0 + w * 32 + qloc) * HD + q5;
            out[rowb]      = O0[reg] * ir;
            out[rowb + 32] = O1[reg] * ir;
        }
    } else {
        float* dest = pO + ((size_t)slot * 128 + w * 32) * HD + q5;
#pragma unroll
        for (int reg = 0; reg < 16; ++reg) {
            int qloc = (reg & 3) + 8 * (reg >> 2) + 4 * hi;
            dest[(size_t)qloc * HD]      = O0[reg];
            dest[(size_t)qloc * HD + 32] = O1[reg];
        }
        if (hi == 0) stS[slot * 128 + w * 32 + q5] = ltot;
    }
}

// ---------------------------------------------------------------------------
// Merge: rows with mq>=4 only (2..8 segments). 64 rows/block, 4 threads/row.
// grid = 8 batches x 56 blocks = 448.
// ---------------------------------------------------------------------------
__global__ __launch_bounds__(256) void merge_kernel(
    float* __restrict__ out, const float* __restrict__ pO,
    const float* __restrict__ stS)
{
    const int tid = threadIdx.x;
    const int bx = blockIdx.x;
    const int b = bx / 56, loc = bx - b * 56;
    const int t = 512 + loc * 64 + (tid >> 2);       // row within batch
    const int dq = (tid & 3) * 16;
    const int mq = t >> 7, rr = t & 127;
    const int nseg = (mq + 4) >> 2;                  // ceil((2mq+2)/8)
    const int sb = b * SLOTS_PER_B + slot_base(mq);

    float denom = 0.f;
    for (int s = 0; s < nseg; ++s) denom += stS[(sb + s) * 128 + rr];
    float inv = 1.0f / denom;

    float4 o[4] = {};
    for (int s = 0; s < nseg; ++s) {
        const float4* pp = (const float4*)
            &pO[((size_t)(sb + s) * 128 + rr) * HD + dq];
#pragma unroll
        for (int i = 0; i < 4; ++i) {
            float4 p = pp[i];
            o[i].x += p.x; o[i].y += p.y;
            o[i].z += p.z; o[i].w += p.w;
        }
    }
    float4* op = (float4*)&out[((size_t)b * TSEQ + t) * HD + dq];
#pragma unroll
    for (int i = 0; i < 4; ++i) {
        o[i].x *= inv; o[i].y *= inv; o[i].z *= inv; o[i].w *= inv;
        op[i] = o[i];
    }
}

extern "C" void kernel_launch(void* const* d_in, const int* in_sizes, int n_in,
                              void* d_out, int out_size, void* d_ws, size_t ws_size,
                              hipStream_t stream) {
    const float* x  = (const float*)d_in[0];   // [8, 4096, 512]
    const float* Wq = (const float*)d_in[1];   // [512, 64]
    const float* Wk = (const float*)d_in[2];
    const float* Wv = (const float*)d_in[3];
    float* out = (float*)d_out;                // [8, 4096, 64] fp32

    short* q  = (short*)d_ws;                  // bf16 [8*4096][64], pre-scaled (incl log2e)
    short* k  = q + QSZ;                       // bf16 [8*4096][64]
    short* vt = k + QSZ;                       // bf16 [8][64][4096] (transposed)
    short* wimg = vt + QSZ;                    // 4 x chunk image [192][136] bf16
    float* pO = (float*)(wimg + 4 * WIMG);     // 1152 slots x [128][64] fp32 = 37.7 MB
    float* stS = pO + (size_t)NB * SLOTS_PER_B * 128 * HD;  // 1152 x 128 denominators

    wtr_kernel<<<dim3(8, 3), 256, 0, stream>>>(Wq, Wk, Wv, wimg);
    qkv_mfma<<<dim3(NB * TSEQ / 64), 256, 0, stream>>>(x, wimg, q, k, vt);
    flash_mfma<<<dim3(NB * SLOTS_PER_B * 4), 64, 0, stream>>>(q, k, vt, out, pO, stS);
    merge_kernel<<<dim3(448), 256, 0, stream>>>(out, pO, stS);
}